// Round 14
// baseline (255.364 us; speedup 1.0000x reference)
//
#include <hip/hip_runtime.h>
#include <hip/hip_bf16.h>

typedef __bf16 bf16x8 __attribute__((ext_vector_type(8)));
typedef float f32x4 __attribute__((ext_vector_type(4)));
typedef unsigned short us;

__device__ __forceinline__ us f2bf(float f) {
  unsigned int u = __float_as_uint(f);
  u += 0x7fffu + ((u >> 16) & 1u);
  return (us)(u >> 16);
}

__device__ __forceinline__ unsigned int pack2(float lo, float hi) {
  __hip_bfloat162 h = __float22bfloat162_rn(float2{lo, hi});
  return *(unsigned int*)&h;
}

__device__ __forceinline__ void load_lds16(const void* g, void* l) {
  __builtin_amdgcn_global_load_lds(
      (const __attribute__((address_space(1))) unsigned int*)g,
      (__attribute__((address_space(3))) unsigned int*)l, 16, 0, 0);
}

// ---------------- fused prep: x->bf16 + 4 weight transposes, one dispatch ----------------
__global__ void prep(const float* __restrict__ x,
                     const float* __restrict__ Wq, const float* __restrict__ Wk,
                     const float* __restrict__ Wv, const float* __restrict__ Wo,
                     us* __restrict__ xb, us* __restrict__ WqkvT, us* __restrict__ WoT) {
  __shared__ float tile[32][33];
  const int blk = blockIdx.x;
  if (blk < 8192) {
    size_t i = ((size_t)blk * 256 + threadIdx.x) * 4;
    float4 v = *(const float4*)(x + i);
    ushort4 o;
    o.x = f2bf(v.x); o.y = f2bf(v.y); o.z = f2bf(v.z); o.w = f2bf(v.w);
    *(ushort4*)(xb + i) = o;
    return;
  }
  const float* in;
  us* out;
  int ldin, ldout, bx, by;
  if (blk < 12288) {
    const int u = blk - 8192;
    in = Wq; out = WqkvT; ldin = 2048; ldout = 2048; bx = u & 63; by = u >> 6;
  } else if (blk < 13312) {
    const int u = blk - 12288;
    in = Wk; out = WqkvT + (size_t)2048 * 2048; ldin = 512; ldout = 2048; bx = u & 15; by = u >> 4;
  } else if (blk < 14336) {
    const int u = blk - 13312;
    in = Wv; out = WqkvT + (size_t)2560 * 2048; ldin = 512; ldout = 2048; bx = u & 15; by = u >> 4;
  } else {
    const int u = blk - 14336;
    in = Wo; out = WoT; ldin = 2048; ldout = 2048; bx = u & 63; by = u >> 6;
  }
  const int c0 = bx * 32, r0 = by * 32;
  const int tx = threadIdx.x & 31, ty = threadIdx.x >> 5;
#pragma unroll
  for (int j = 0; j < 4; ++j)
    tile[ty + j * 8][tx] = in[(size_t)(r0 + ty + j * 8) * ldin + c0 + tx];
  __syncthreads();
#pragma unroll
  for (int j = 0; j < 4; ++j)
    out[(size_t)(c0 + ty + j * 8) * ldout + r0 + tx] = f2bf(tile[tx][ty + j * 8]);
}

// ---------------- V slice of QKV -> VT [b*4+kv][128][2048] ----------------
__global__ void tr_v(const us* __restrict__ QKV, us* __restrict__ VT) {
  __shared__ us tile[32][33];
  const int z = blockIdx.z, b = z >> 2, kvh = z & 3;
  const us* in = QKV + (size_t)(b * 2048) * 3072 + 2560 + kvh * 128;
  us* out = VT + (size_t)z * 128 * 2048;
  const int c0 = blockIdx.x * 32, r0 = blockIdx.y * 32;
  const int tx = threadIdx.x, ty = threadIdx.y;
#pragma unroll
  for (int j = 0; j < 4; ++j)
    tile[ty + j * 8][tx] = in[(size_t)(r0 + ty + j * 8) * 3072 + c0 + tx];
  __syncthreads();
#pragma unroll
  for (int j = 0; j < 4; ++j)
    out[(size_t)(c0 + ty + j * 8) * 2048 + r0 + tx] = tile[tx][ty + j * 8];
}

// ---------------- bf16 GEMM 256x(64*NF), 2-phase/K-tile, counted vmcnt + XCD swizzle ----------------
template <int NF, int OUTF32>
__global__ __launch_bounds__(512, 2) void gemm256(const us* __restrict__ A,
                                                  const us* __restrict__ B,
                                                  void* __restrict__ Cv, int M, int N, int K) {
  __shared__ __attribute__((aligned(16))) us Ah[2][2][256 * 32];
  __shared__ __attribute__((aligned(16))) us Bf[2][64 * NF * 64];
  const int tid = threadIdx.x;
  const int lane = tid & 63;
  const int cl = lane & 15, rg = lane >> 4;
  const int wave = tid >> 6;
  const int wm = wave >> 2, wn = wave & 3;
  const int nwg = gridDim.x * gridDim.y;
  const int bid = blockIdx.x + gridDim.x * blockIdx.y;
  const int swz = (bid & 7) * (nwg >> 3) + (bid >> 3);
  const int bn = swz % gridDim.x, bm = swz / gridDim.x;
  const int NK = K >> 6;
  const int rowA = bm * 256, rowB = bn * (64 * NF);

  f32x4 acc[8][NF] = {};

  auto stage_A = [&](int bf, int h, int kt) {
#pragma unroll
    for (int i = 0; i < 2; ++i) {
      const int L = i * 512 + tid;
      const int r = L >> 2;
      const int c = (L & 3) ^ ((r >> 1) & 3);
      load_lds16(A + (size_t)(rowA + r) * K + kt * 64 + h * 32 + c * 8,
                 &Ah[bf][h][(size_t)(i * 512 + (tid & ~63)) * 8]);
    }
  };
  auto stage_B = [&](int bf, int kt) {
#pragma unroll
    for (int i = 0; i < NF; ++i) {
      const int L = i * 512 + tid;
      const int r = L >> 3;
      const int c = (L & 7) ^ (r & 7);
      load_lds16(B + (size_t)(rowB + r) * K + kt * 64 + c * 8,
                 &Bf[bf][(size_t)(i * 512 + (tid & ~63)) * 8]);
    }
  };

  stage_B(0, 0);
  stage_A(0, 0, 0);
  stage_A(0, 1, 0);
  asm volatile("s_waitcnt vmcnt(2)" ::: "memory");
  __builtin_amdgcn_s_barrier();

  int buf = 0;
#pragma unroll 1
  for (int kt = 0; kt < NK; ++kt) {
    const bool nl = (kt + 1 < NK);
    bf16x8 af[8], bfr[NF];

    // ---- PH0: kk = 0 ----
#pragma unroll
    for (int f = 0; f < 8; ++f) {
      const int r = 128 * wm + 16 * f + cl;
      af[f] = *(const bf16x8*)(&Ah[buf][0][(r * 4 + (rg ^ ((r >> 1) & 3))) * 8]);
    }
#pragma unroll
    for (int nf = 0; nf < NF; ++nf) {
      const int r = 16 * NF * wn + 16 * nf + cl;
      bfr[nf] = *(const bf16x8*)(&Bf[buf][(r * 8 + (rg ^ (r & 7))) * 8]);
    }
    if (nl) stage_B(buf ^ 1, kt + 1);
    __builtin_amdgcn_s_barrier();
    asm volatile("s_waitcnt lgkmcnt(0)" ::: "memory");
    __builtin_amdgcn_s_setprio(1);
#pragma unroll
    for (int f = 0; f < 8; ++f)
#pragma unroll
      for (int nf = 0; nf < NF; ++nf)
        acc[f][nf] = __builtin_amdgcn_mfma_f32_16x16x32_bf16(af[f], bfr[nf], acc[f][nf], 0, 0, 0);
    __builtin_amdgcn_s_setprio(0);
    if (nl) {
      if constexpr (NF == 3) { asm volatile("s_waitcnt vmcnt(3)" ::: "memory"); }
      else                   { asm volatile("s_waitcnt vmcnt(2)" ::: "memory"); }
    } else {
      asm volatile("s_waitcnt vmcnt(0)" ::: "memory");
    }
    __builtin_amdgcn_s_barrier();

    // ---- PH1: kk = 1 ----
#pragma unroll
    for (int f = 0; f < 8; ++f) {
      const int r = 128 * wm + 16 * f + cl;
      af[f] = *(const bf16x8*)(&Ah[buf][1][(r * 4 + (rg ^ ((r >> 1) & 3))) * 8]);
    }
#pragma unroll
    for (int nf = 0; nf < NF; ++nf) {
      const int r = 16 * NF * wn + 16 * nf + cl;
      bfr[nf] = *(const bf16x8*)(&Bf[buf][(r * 8 + ((4 + rg) ^ (r & 7))) * 8]);
    }
    if (nl) { stage_A(buf ^ 1, 0, kt + 1); stage_A(buf ^ 1, 1, kt + 1); }
    __builtin_amdgcn_s_barrier();
    asm volatile("s_waitcnt lgkmcnt(0)" ::: "memory");
    __builtin_amdgcn_s_setprio(1);
#pragma unroll
    for (int f = 0; f < 8; ++f)
#pragma unroll
      for (int nf = 0; nf < NF; ++nf)
        acc[f][nf] = __builtin_amdgcn_mfma_f32_16x16x32_bf16(af[f], bfr[nf], acc[f][nf], 0, 0, 0);
    __builtin_amdgcn_s_setprio(0);
    if (nl) asm volatile("s_waitcnt vmcnt(2)" ::: "memory");
    __builtin_amdgcn_s_barrier();

    buf ^= 1;
  }

#pragma unroll
  for (int f = 0; f < 8; ++f)
#pragma unroll
    for (int nf = 0; nf < NF; ++nf)
#pragma unroll
      for (int i = 0; i < 4; ++i) {
        const int row = bm * 256 + wm * 128 + f * 16 + rg * 4 + i;
        const int col = bn * 64 * NF + wn * 16 * NF + nf * 16 + cl;
        if (OUTF32)
          ((float*)Cv)[(size_t)row * N + col] = acc[f][nf][i];
        else
          ((us*)Cv)[(size_t)row * N + col] = f2bf(acc[f][nf][i]);
      }
}

// ---- causal GQA flash attention: r5 per-wave code, 48 KiB LDS (single-buffer V), 3 blocks/CU ----
// Grid 32 jt x 16 h x 2 b = 1024 blocks, heavy-first (jt = 31-blockIdx.x); no pairing.
// K double-buffered (prefetch at top of iter); V single-buffered: PV -> barrier ->
// restage V(kt+1) -> barrier. LDS 48 KiB => 3 blocks/CU (was 2).
__global__ __launch_bounds__(256, 3) void attn(const us* __restrict__ QKV,
                                               const us* __restrict__ VT,
                                               us* __restrict__ O) {
  __shared__ __attribute__((aligned(16))) us Ks[2][64 * 128];
  __shared__ __attribute__((aligned(16))) us VTs[128 * 64];
  const int T = 2048, LD = 3072, D = 2048;
  const int jt = 31 - blockIdx.x;
  const int h = blockIdx.y, b = blockIdx.z;
  const int kvh = h >> 2;
  const int tid = threadIdx.x, lane = tid & 63, wave = tid >> 6;
  const int cl = lane & 15, rg = lane >> 4;
  const bool abit = (lane & 16) != 0, bbit = (lane & 32) != 0;
  const bool ab = abit != bbit;
  const us* Kbase = QKV + (size_t)b * T * LD + 2048 + kvh * 128;
  const us* Vbase = VT + (size_t)(b * 4 + kvh) * 128 * T;

  auto stage_K = [&](int sb, int k0) {
#pragma unroll
    for (int i = 0; i < 4; ++i) {
      const int Ls = i * 256 + tid;
      const int r = Ls >> 4, s = Ls & 15, c = s ^ (r & 7);
      load_lds16(Kbase + (size_t)(k0 + r) * LD + c * 8,
                 &Ks[sb][(i * 256 + (tid & 0xC0)) * 8]);
    }
  };
  auto stage_V = [&](int k0) {
#pragma unroll
    for (int i = 0; i < 4; ++i) {
      const int Ls = i * 256 + tid;
      const int r = Ls >> 3, s = Ls & 7, c = s ^ (r & 7);
      load_lds16(Vbase + (size_t)r * T + k0 + c * 8,
                 &VTs[(i * 256 + (tid & 0xC0)) * 8]);
    }
  };

  const float scale = 0.08838834764831845f;  // 1/sqrt(128)
  const int q0 = jt * 64;
  const int nkt = jt + 1;
  const int qrow = q0 + wave * 16 + cl;

  const us* Qp = QKV + (size_t)(b * T + qrow) * LD + h * 128;
  bf16x8 qf[4];
#pragma unroll
  for (int ks = 0; ks < 4; ++ks) qf[ks] = *(const bf16x8*)(Qp + ks * 32 + rg * 8);

  f32x4 o[8] = {};
  float m = -1e30f, l = 0.f;
  int buf = 0;

  stage_K(0, 0);
  stage_V(0);
  __syncthreads();

#pragma unroll 1
  for (int kt = 0; kt < nkt; ++kt) {
    if (kt + 1 < nkt) stage_K(buf ^ 1, (kt + 1) * 64);

    f32x4 sa[4] = {};
    __builtin_amdgcn_s_setprio(1);
#pragma unroll
    for (int ks = 0; ks < 4; ++ks) {
#pragma unroll
      for (int n = 0; n < 4; ++n) {
        const int row = n * 16 + cl;
        const int p = (ks * 4 + rg) ^ (row & 7);
        const bf16x8 kf = *(const bf16x8*)(&Ks[buf][row * 128 + p * 8]);
        sa[n] = __builtin_amdgcn_mfma_f32_16x16x32_bf16(kf, qf[ks], sa[n], 0, 0, 0);
      }
    }
    __builtin_amdgcn_s_setprio(0);

    const int k0 = kt * 64;
    float p[4][4];
    float pmax = -1e30f;
    if (kt == jt) {
#pragma unroll
      for (int n = 0; n < 4; ++n)
#pragma unroll
        for (int i = 0; i < 4; ++i) {
          const int kg = k0 + n * 16 + rg * 4 + i;
          p[n][i] = (kg > qrow) ? -1e30f : sa[n][i] * scale;
          pmax = fmaxf(pmax, p[n][i]);
        }
    } else {
#pragma unroll
      for (int n = 0; n < 4; ++n)
#pragma unroll
        for (int i = 0; i < 4; ++i) {
          p[n][i] = sa[n][i] * scale;
          pmax = fmaxf(pmax, p[n][i]);
        }
    }
    pmax = fmaxf(pmax, __shfl_xor(pmax, 16));
    pmax = fmaxf(pmax, __shfl_xor(pmax, 32));

    if (!__all(pmax <= m + 8.f)) {  // T13 defer-max
      const float mnew = fmaxf(m, pmax);
      const float alpha = __expf(m - mnew);
      m = mnew;
      l *= alpha;
#pragma unroll
      for (int n2 = 0; n2 < 8; ++n2) o[n2] *= alpha;
    }

    float rs = 0.f;
#pragma unroll
    for (int n = 0; n < 4; ++n)
#pragma unroll
      for (int i = 0; i < 4; ++i) {
        p[n][i] = __expf(p[n][i] - m);
        rs += p[n][i];
      }
    rs += __shfl_xor(rs, 16);
    rs += __shfl_xor(rs, 32);
    l += rs;

    unsigned int F[2][4];
#pragma unroll
    for (int ks2 = 0; ks2 < 2; ++ks2) {
      const unsigned int pk00 = pack2(p[2 * ks2][0], p[2 * ks2][1]);
      const unsigned int pk01 = pack2(p[2 * ks2][2], p[2 * ks2][3]);
      const unsigned int pk10 = pack2(p[2 * ks2 + 1][0], p[2 * ks2 + 1][1]);
      const unsigned int pk11 = pack2(p[2 * ks2 + 1][2], p[2 * ks2 + 1][3]);
      const unsigned int s0 = bbit ? pk00 : pk10;
      const unsigned int s1 = bbit ? pk01 : pk11;
      const unsigned int r0 = (unsigned int)__shfl_xor((int)s0, 32);
      const unsigned int r1 = (unsigned int)__shfl_xor((int)s1, 32);
      const unsigned int gk0 = bbit ? pk10 : pk00;
      const unsigned int gk1 = bbit ? pk11 : pk01;
      const unsigned int t0 = ab ? gk0 : r0;
      const unsigned int t1 = ab ? gk1 : r1;
      const unsigned int u0 = (unsigned int)__shfl_xor((int)t0, 16);
      const unsigned int u1 = (unsigned int)__shfl_xor((int)t1, 16);
      const unsigned int k20 = ab ? r0 : gk0;
      const unsigned int k21 = ab ? r1 : gk1;
      F[ks2][0] = abit ? u0 : k20;
      F[ks2][1] = abit ? u1 : k21;
      F[ks2][2] = abit ? k20 : u0;
      F[ks2][3] = abit ? k21 : u1;
    }

    __builtin_amdgcn_s_setprio(1);
#pragma unroll
    for (int ks2 = 0; ks2 < 2; ++ks2) {
      uint4 fu = make_uint4(F[ks2][0], F[ks2][1], F[ks2][2], F[ks2][3]);
      const bf16x8 pf = *(const bf16x8*)&fu;
#pragma unroll
      for (int n2 = 0; n2 < 8; ++n2) {
        const int dr = n2 * 16 + cl;
        const int p2 = (ks2 * 4 + rg) ^ (dr & 7);
        const bf16x8 vf = *(const bf16x8*)(&VTs[dr * 64 + p2 * 8]);
        o[n2] = __builtin_amdgcn_mfma_f32_16x16x32_bf16(vf, pf, o[n2], 0, 0, 0);
      }
    }
    __builtin_amdgcn_s_setprio(0);

    __syncthreads();  // all waves done reading VTs (and Ks[buf])
    if (kt + 1 < nkt) stage_V((kt + 1) * 64);
    __syncthreads();  // V(kt+1) + K(kt+1) staged and visible
    buf ^= 1;
  }

  const float rl = __builtin_amdgcn_rcpf(l);
#pragma unroll
  for (int n2 = 0; n2 < 8; ++n2) {
    ushort4 ov;
    ov.x = f2bf(o[n2][0] * rl);
    ov.y = f2bf(o[n2][1] * rl);
    ov.z = f2bf(o[n2][2] * rl);
    ov.w = f2bf(o[n2][3] * rl);
    *(ushort4*)(O + (size_t)(b * T + qrow) * D + h * 128 + n2 * 16 + rg * 4) = ov;
  }
}

extern "C" void kernel_launch(void* const* d_in, const int* in_sizes, int n_in,
                              void* d_out, int out_size, void* d_ws, size_t ws_size,
                              hipStream_t stream) {
  const float* x = (const float*)d_in[0];
  const float* Wq = (const float*)d_in[1];
  const float* Wk = (const float*)d_in[2];
  const float* Wv = (const float*)d_in[3];
  const float* Wo = (const float*)d_in[4];
  float* out = (float*)d_out;

  char* ws = (char*)d_ws;
  us* xb    = (us*)(ws);                 // x bf16, later attn O
  us* WqkvT = (us*)(ws + 16777216);      // [3072][2048]
  us* WoT   = (us*)(ws + 29360128);      // [2048][2048]
  us* QKV   = (us*)(ws + 37748736);      // [4096][3072]
  us* VTb   = (us*)(ws + 62914560);      // [8][128][2048]

  prep<<<dim3(18432), dim3(256), 0, stream>>>(x, Wq, Wk, Wv, Wo, xb, WqkvT, WoT);
  gemm256<3, 0><<<dim3(16, 16), dim3(512), 0, stream>>>(xb, WqkvT, QKV, 4096, 3072, 2048);
  tr_v<<<dim3(4, 64, 8), dim3(32, 8), 0, stream>>>(QKV, VTb);
  attn<<<dim3(32, 16, 2), dim3(256), 0, stream>>>(QKV, VTb, xb);
  gemm256<2, 1><<<dim3(16, 16), dim3(512), 0, stream>>>(xb, WoT, out, 4096, 2048, 2048);
}

// Round 15
// 188.437 us; speedup vs baseline: 1.3552x; 1.3552x over previous
//
#include <hip/hip_runtime.h>
#include <hip/hip_bf16.h>

typedef __bf16 bf16x8 __attribute__((ext_vector_type(8)));
typedef float f32x4 __attribute__((ext_vector_type(4)));
typedef unsigned short us;

__device__ __forceinline__ us f2bf(float f) {
  unsigned int u = __float_as_uint(f);
  u += 0x7fffu + ((u >> 16) & 1u);
  return (us)(u >> 16);
}

__device__ __forceinline__ unsigned int pack2(float lo, float hi) {
  __hip_bfloat162 h = __float22bfloat162_rn(float2{lo, hi});
  return *(unsigned int*)&h;
}

__device__ __forceinline__ void load_lds16(const void* g, void* l) {
  __builtin_amdgcn_global_load_lds(
      (const __attribute__((address_space(1))) unsigned int*)g,
      (__attribute__((address_space(3))) unsigned int*)l, 16, 0, 0);
}

// ---------------- fused prep: x->bf16 + 4 weight transposes, one dispatch ----------------
__global__ void prep(const float* __restrict__ x,
                     const float* __restrict__ Wq, const float* __restrict__ Wk,
                     const float* __restrict__ Wv, const float* __restrict__ Wo,
                     us* __restrict__ xb, us* __restrict__ WqkvT, us* __restrict__ WoT) {
  __shared__ float tile[32][33];
  const int blk = blockIdx.x;
  if (blk < 8192) {
    size_t i = ((size_t)blk * 256 + threadIdx.x) * 4;
    float4 v = *(const float4*)(x + i);
    ushort4 o;
    o.x = f2bf(v.x); o.y = f2bf(v.y); o.z = f2bf(v.z); o.w = f2bf(v.w);
    *(ushort4*)(xb + i) = o;
    return;
  }
  const float* in;
  us* out;
  int ldin, ldout, bx, by;
  if (blk < 12288) {
    const int u = blk - 8192;
    in = Wq; out = WqkvT; ldin = 2048; ldout = 2048; bx = u & 63; by = u >> 6;
  } else if (blk < 13312) {
    const int u = blk - 12288;
    in = Wk; out = WqkvT + (size_t)2048 * 2048; ldin = 512; ldout = 2048; bx = u & 15; by = u >> 4;
  } else if (blk < 14336) {
    const int u = blk - 13312;
    in = Wv; out = WqkvT + (size_t)2560 * 2048; ldin = 512; ldout = 2048; bx = u & 15; by = u >> 4;
  } else {
    const int u = blk - 14336;
    in = Wo; out = WoT; ldin = 2048; ldout = 2048; bx = u & 63; by = u >> 6;
  }
  const int c0 = bx * 32, r0 = by * 32;
  const int tx = threadIdx.x & 31, ty = threadIdx.x >> 5;
#pragma unroll
  for (int j = 0; j < 4; ++j)
    tile[ty + j * 8][tx] = in[(size_t)(r0 + ty + j * 8) * ldin + c0 + tx];
  __syncthreads();
#pragma unroll
  for (int j = 0; j < 4; ++j)
    out[(size_t)(c0 + ty + j * 8) * ldout + r0 + tx] = f2bf(tile[tx][ty + j * 8]);
}

// ---------------- V slice of QKV -> VT [b*4+kv][128][2048] ----------------
__global__ void tr_v(const us* __restrict__ QKV, us* __restrict__ VT) {
  __shared__ us tile[32][33];
  const int z = blockIdx.z, b = z >> 2, kvh = z & 3;
  const us* in = QKV + (size_t)(b * 2048) * 3072 + 2560 + kvh * 128;
  us* out = VT + (size_t)z * 128 * 2048;
  const int c0 = blockIdx.x * 32, r0 = blockIdx.y * 32;
  const int tx = threadIdx.x, ty = threadIdx.y;
#pragma unroll
  for (int j = 0; j < 4; ++j)
    tile[ty + j * 8][tx] = in[(size_t)(r0 + ty + j * 8) * 3072 + c0 + tx];
  __syncthreads();
#pragma unroll
  for (int j = 0; j < 4; ++j)
    out[(size_t)(c0 + ty + j * 8) * 2048 + r0 + tx] = tile[tx][ty + j * 8];
}

// ---------------- bf16 GEMM 256x(64*NF), 2-phase/K-tile, counted vmcnt + XCD swizzle ----------------
template <int NF, int OUTF32>
__global__ __launch_bounds__(512, 2) void gemm256(const us* __restrict__ A,
                                                  const us* __restrict__ B,
                                                  void* __restrict__ Cv, int M, int N, int K) {
  __shared__ __attribute__((aligned(16))) us Ah[2][2][256 * 32];
  __shared__ __attribute__((aligned(16))) us Bf[2][64 * NF * 64];
  const int tid = threadIdx.x;
  const int lane = tid & 63;
  const int cl = lane & 15, rg = lane >> 4;
  const int wave = tid >> 6;
  const int wm = wave >> 2, wn = wave & 3;
  const int nwg = gridDim.x * gridDim.y;
  const int bid = blockIdx.x + gridDim.x * blockIdx.y;
  const int swz = (bid & 7) * (nwg >> 3) + (bid >> 3);
  const int bn = swz % gridDim.x, bm = swz / gridDim.x;
  const int NK = K >> 6;
  const int rowA = bm * 256, rowB = bn * (64 * NF);

  f32x4 acc[8][NF] = {};

  auto stage_A = [&](int bf, int h, int kt) {
#pragma unroll
    for (int i = 0; i < 2; ++i) {
      const int L = i * 512 + tid;
      const int r = L >> 2;
      const int c = (L & 3) ^ ((r >> 1) & 3);
      load_lds16(A + (size_t)(rowA + r) * K + kt * 64 + h * 32 + c * 8,
                 &Ah[bf][h][(size_t)(i * 512 + (tid & ~63)) * 8]);
    }
  };
  auto stage_B = [&](int bf, int kt) {
#pragma unroll
    for (int i = 0; i < NF; ++i) {
      const int L = i * 512 + tid;
      const int r = L >> 3;
      const int c = (L & 7) ^ (r & 7);
      load_lds16(B + (size_t)(rowB + r) * K + kt * 64 + c * 8,
                 &Bf[bf][(size_t)(i * 512 + (tid & ~63)) * 8]);
    }
  };

  stage_B(0, 0);
  stage_A(0, 0, 0);
  stage_A(0, 1, 0);
  asm volatile("s_waitcnt vmcnt(2)" ::: "memory");
  __builtin_amdgcn_s_barrier();

  int buf = 0;
#pragma unroll 1
  for (int kt = 0; kt < NK; ++kt) {
    const bool nl = (kt + 1 < NK);
    bf16x8 af[8], bfr[NF];

    // ---- PH0: kk = 0 ----
#pragma unroll
    for (int f = 0; f < 8; ++f) {
      const int r = 128 * wm + 16 * f + cl;
      af[f] = *(const bf16x8*)(&Ah[buf][0][(r * 4 + (rg ^ ((r >> 1) & 3))) * 8]);
    }
#pragma unroll
    for (int nf = 0; nf < NF; ++nf) {
      const int r = 16 * NF * wn + 16 * nf + cl;
      bfr[nf] = *(const bf16x8*)(&Bf[buf][(r * 8 + (rg ^ (r & 7))) * 8]);
    }
    if (nl) stage_B(buf ^ 1, kt + 1);
    __builtin_amdgcn_s_barrier();
    asm volatile("s_waitcnt lgkmcnt(0)" ::: "memory");
    __builtin_amdgcn_s_setprio(1);
#pragma unroll
    for (int f = 0; f < 8; ++f)
#pragma unroll
      for (int nf = 0; nf < NF; ++nf)
        acc[f][nf] = __builtin_amdgcn_mfma_f32_16x16x32_bf16(af[f], bfr[nf], acc[f][nf], 0, 0, 0);
    __builtin_amdgcn_s_setprio(0);
    if (nl) {
      if constexpr (NF == 3) { asm volatile("s_waitcnt vmcnt(3)" ::: "memory"); }
      else                   { asm volatile("s_waitcnt vmcnt(2)" ::: "memory"); }
    } else {
      asm volatile("s_waitcnt vmcnt(0)" ::: "memory");
    }
    __builtin_amdgcn_s_barrier();

    // ---- PH1: kk = 1 ----
#pragma unroll
    for (int f = 0; f < 8; ++f) {
      const int r = 128 * wm + 16 * f + cl;
      af[f] = *(const bf16x8*)(&Ah[buf][1][(r * 4 + (rg ^ ((r >> 1) & 3))) * 8]);
    }
#pragma unroll
    for (int nf = 0; nf < NF; ++nf) {
      const int r = 16 * NF * wn + 16 * nf + cl;
      bfr[nf] = *(const bf16x8*)(&Bf[buf][(r * 8 + ((4 + rg) ^ (r & 7))) * 8]);
    }
    if (nl) { stage_A(buf ^ 1, 0, kt + 1); stage_A(buf ^ 1, 1, kt + 1); }
    __builtin_amdgcn_s_barrier();
    asm volatile("s_waitcnt lgkmcnt(0)" ::: "memory");
    __builtin_amdgcn_s_setprio(1);
#pragma unroll
    for (int f = 0; f < 8; ++f)
#pragma unroll
      for (int nf = 0; nf < NF; ++nf)
        acc[f][nf] = __builtin_amdgcn_mfma_f32_16x16x32_bf16(af[f], bfr[nf], acc[f][nf], 0, 0, 0);
    __builtin_amdgcn_s_setprio(0);
    if (nl) asm volatile("s_waitcnt vmcnt(2)" ::: "memory");
    __builtin_amdgcn_s_barrier();

    buf ^= 1;
  }

#pragma unroll
  for (int f = 0; f < 8; ++f)
#pragma unroll
    for (int nf = 0; nf < NF; ++nf)
#pragma unroll
      for (int i = 0; i < 4; ++i) {
        const int row = bm * 256 + wm * 128 + f * 16 + rg * 4 + i;
        const int col = bn * 64 * NF + wn * 16 * NF + nf * 16 + cl;
        if (OUTF32)
          ((float*)Cv)[(size_t)row * N + col] = acc[f][nf][i];
        else
          ((us*)Cv)[(size_t)row * N + col] = f2bf(acc[f][nf][i]);
      }
}

// ---------------- causal GQA flash attention (round-5 version: measured best, 76 us) ----------------
__global__ __launch_bounds__(256, 2) void attn(const us* __restrict__ QKV,
                                               const us* __restrict__ VT,
                                               us* __restrict__ O) {
  __shared__ __attribute__((aligned(16))) us Ks[2][64 * 128];
  __shared__ __attribute__((aligned(16))) us VTs[2][128 * 64];
  const int T = 2048, LD = 3072, D = 2048;
  const int jp = blockIdx.x, h = blockIdx.y, b = blockIdx.z;
  const int kvh = h >> 2;
  const int tid = threadIdx.x, lane = tid & 63, wave = tid >> 6;
  const int cl = lane & 15, rg = lane >> 4;
  const bool abit = (lane & 16) != 0, bbit = (lane & 32) != 0;
  const bool ab = abit != bbit;
  const us* Kbase = QKV + (size_t)b * T * LD + 2048 + kvh * 128;
  const us* Vbase = VT + (size_t)(b * 4 + kvh) * 128 * T;

  auto stage = [&](int sb, int k0) {
#pragma unroll
    for (int i = 0; i < 4; ++i) {
      const int Ls = i * 256 + tid;
      const int r = Ls >> 4, s = Ls & 15, c = s ^ (r & 7);
      load_lds16(Kbase + (size_t)(k0 + r) * LD + c * 8,
                 &Ks[sb][(i * 256 + (tid & 0xC0)) * 8]);
    }
#pragma unroll
    for (int i = 0; i < 4; ++i) {
      const int Ls = i * 256 + tid;
      const int r = Ls >> 3, s = Ls & 7, c = s ^ (r & 7);
      load_lds16(Vbase + (size_t)r * T + k0 + c * 8,
                 &VTs[sb][(i * 256 + (tid & 0xC0)) * 8]);
    }
  };

  const float scale = 0.08838834764831845f;  // 1/sqrt(128)

#pragma unroll 1
  for (int pass = 0; pass < 2; ++pass) {
    const int jt = pass ? (31 - jp) : jp;
    const int q0 = jt * 64;
    const int nkt = jt + 1;
    const int qrow = q0 + wave * 16 + cl;

    const us* Qp = QKV + (size_t)(b * T + qrow) * LD + h * 128;
    bf16x8 qf[4];
#pragma unroll
    for (int ks = 0; ks < 4; ++ks) qf[ks] = *(const bf16x8*)(Qp + ks * 32 + rg * 8);

    f32x4 o[8] = {};
    float m = -1e30f, l = 0.f;
    int buf = 0;

    stage(0, 0);
    __syncthreads();

#pragma unroll 1
    for (int kt = 0; kt < nkt; ++kt) {
      if (kt + 1 < nkt) stage(buf ^ 1, (kt + 1) * 64);

      f32x4 sa[4] = {};
      __builtin_amdgcn_s_setprio(1);
#pragma unroll
      for (int ks = 0; ks < 4; ++ks) {
#pragma unroll
        for (int n = 0; n < 4; ++n) {
          const int row = n * 16 + cl;
          const int p = (ks * 4 + rg) ^ (row & 7);
          const bf16x8 kf = *(const bf16x8*)(&Ks[buf][row * 128 + p * 8]);
          sa[n] = __builtin_amdgcn_mfma_f32_16x16x32_bf16(kf, qf[ks], sa[n], 0, 0, 0);
        }
      }
      __builtin_amdgcn_s_setprio(0);

      const int k0 = kt * 64;
      float p[4][4];
      float pmax = -1e30f;
      if (kt == jt) {
#pragma unroll
        for (int n = 0; n < 4; ++n)
#pragma unroll
          for (int i = 0; i < 4; ++i) {
            const int kg = k0 + n * 16 + rg * 4 + i;
            p[n][i] = (kg > qrow) ? -1e30f : sa[n][i] * scale;
            pmax = fmaxf(pmax, p[n][i]);
          }
      } else {
#pragma unroll
        for (int n = 0; n < 4; ++n)
#pragma unroll
          for (int i = 0; i < 4; ++i) {
            p[n][i] = sa[n][i] * scale;
            pmax = fmaxf(pmax, p[n][i]);
          }
      }
      pmax = fmaxf(pmax, __shfl_xor(pmax, 16));
      pmax = fmaxf(pmax, __shfl_xor(pmax, 32));

      if (!__all(pmax <= m + 8.f)) {  // T13 defer-max
        const float mnew = fmaxf(m, pmax);
        const float alpha = __expf(m - mnew);
        m = mnew;
        l *= alpha;
#pragma unroll
        for (int n2 = 0; n2 < 8; ++n2) o[n2] *= alpha;
      }

      float rs = 0.f;
#pragma unroll
      for (int n = 0; n < 4; ++n)
#pragma unroll
        for (int i = 0; i < 4; ++i) {
          p[n][i] = __expf(p[n][i] - m);
          rs += p[n][i];
        }
      rs += __shfl_xor(rs, 16);
      rs += __shfl_xor(rs, 32);
      l += rs;

      unsigned int F[2][4];
#pragma unroll
      for (int ks2 = 0; ks2 < 2; ++ks2) {
        const unsigned int pk00 = pack2(p[2 * ks2][0], p[2 * ks2][1]);
        const unsigned int pk01 = pack2(p[2 * ks2][2], p[2 * ks2][3]);
        const unsigned int pk10 = pack2(p[2 * ks2 + 1][0], p[2 * ks2 + 1][1]);
        const unsigned int pk11 = pack2(p[2 * ks2 + 1][2], p[2 * ks2 + 1][3]);
        const unsigned int s0 = bbit ? pk00 : pk10;
        const unsigned int s1 = bbit ? pk01 : pk11;
        const unsigned int r0 = (unsigned int)__shfl_xor((int)s0, 32);
        const unsigned int r1 = (unsigned int)__shfl_xor((int)s1, 32);
        const unsigned int gk0 = bbit ? pk10 : pk00;
        const unsigned int gk1 = bbit ? pk11 : pk01;
        const unsigned int t0 = ab ? gk0 : r0;
        const unsigned int t1 = ab ? gk1 : r1;
        const unsigned int u0 = (unsigned int)__shfl_xor((int)t0, 16);
        const unsigned int u1 = (unsigned int)__shfl_xor((int)t1, 16);
        const unsigned int k20 = ab ? r0 : gk0;
        const unsigned int k21 = ab ? r1 : gk1;
        F[ks2][0] = abit ? u0 : k20;
        F[ks2][1] = abit ? u1 : k21;
        F[ks2][2] = abit ? k20 : u0;
        F[ks2][3] = abit ? k21 : u1;
      }

      __builtin_amdgcn_s_setprio(1);
#pragma unroll
      for (int ks2 = 0; ks2 < 2; ++ks2) {
        uint4 fu = make_uint4(F[ks2][0], F[ks2][1], F[ks2][2], F[ks2][3]);
        const bf16x8 pf = *(const bf16x8*)&fu;
#pragma unroll
        for (int n2 = 0; n2 < 8; ++n2) {
          const int dr = n2 * 16 + cl;
          const int p2 = (ks2 * 4 + rg) ^ (dr & 7);
          const bf16x8 vf = *(const bf16x8*)(&VTs[buf][dr * 64 + p2 * 8]);
          o[n2] = __builtin_amdgcn_mfma_f32_16x16x32_bf16(vf, pf, o[n2], 0, 0, 0);
        }
      }
      __builtin_amdgcn_s_setprio(0);

      __syncthreads();
      buf ^= 1;
    }

    const float rl = __builtin_amdgcn_rcpf(l);
#pragma unroll
    for (int n2 = 0; n2 < 8; ++n2) {
      ushort4 ov;
      ov.x = f2bf(o[n2][0] * rl);
      ov.y = f2bf(o[n2][1] * rl);
      ov.z = f2bf(o[n2][2] * rl);
      ov.w = f2bf(o[n2][3] * rl);
      *(ushort4*)(O + (size_t)(b * T + qrow) * D + h * 128 + n2 * 16 + rg * 4) = ov;
    }
  }
}

extern "C" void kernel_launch(void* const* d_in, const int* in_sizes, int n_in,
                              void* d_out, int out_size, void* d_ws, size_t ws_size,
                              hipStream_t stream) {
  const float* x = (const float*)d_in[0];
  const float* Wq = (const float*)d_in[1];
  const float* Wk = (const float*)d_in[2];
  const float* Wv = (const float*)d_in[3];
  const float* Wo = (const float*)d_in[4];
  float* out = (float*)d_out;

  char* ws = (char*)d_ws;
  us* xb    = (us*)(ws);                 // x bf16, later attn O
  us* WqkvT = (us*)(ws + 16777216);      // [3072][2048]
  us* WoT   = (us*)(ws + 29360128);      // [2048][2048]
  us* QKV   = (us*)(ws + 37748736);      // [4096][3072]
  us* VTb   = (us*)(ws + 62914560);      // [8][128][2048]

  prep<<<dim3(18432), dim3(256), 0, stream>>>(x, Wq, Wk, Wv, Wo, xb, WqkvT, WoT);
  gemm256<3, 0><<<dim3(16, 16), dim3(512), 0, stream>>>(xb, WqkvT, QKV, 4096, 3072, 2048);
  tr_v<<<dim3(4, 64, 8), dim3(32, 8), 0, stream>>>(QKV, VTb);
  attn<<<dim3(16, 16, 2), dim3(256), 0, stream>>>(QKV, VTb, xb);
  gemm256<2, 1><<<dim3(16, 16), dim3(512), 0, stream>>>(xb, WoT, out, 4096, 2048, 2048);
}

// Round 16
// 186.190 us; speedup vs baseline: 1.3715x; 1.0121x over previous
//
#include <hip/hip_runtime.h>
#include <hip/hip_bf16.h>

typedef __bf16 bf16x8 __attribute__((ext_vector_type(8)));
typedef float f32x4 __attribute__((ext_vector_type(4)));
typedef unsigned short us;

__device__ __forceinline__ us f2bf(float f) {
  unsigned int u = __float_as_uint(f);
  u += 0x7fffu + ((u >> 16) & 1u);
  return (us)(u >> 16);
}

__device__ __forceinline__ unsigned int pack2(float lo, float hi) {
  __hip_bfloat162 h = __float22bfloat162_rn(float2{lo, hi});
  return *(unsigned int*)&h;
}

__device__ __forceinline__ void load_lds16(const void* g, void* l) {
  __builtin_amdgcn_global_load_lds(
      (const __attribute__((address_space(1))) unsigned int*)g,
      (__attribute__((address_space(3))) unsigned int*)l, 16, 0, 0);
}

// ---------------- fused prep: x->bf16 + 4 weight transposes, one dispatch ----------------
__global__ void prep(const float* __restrict__ x,
                     const float* __restrict__ Wq, const float* __restrict__ Wk,
                     const float* __restrict__ Wv, const float* __restrict__ Wo,
                     us* __restrict__ xb, us* __restrict__ WqkvT, us* __restrict__ WoT) {
  __shared__ float tile[32][33];
  const int blk = blockIdx.x;
  if (blk < 8192) {
    size_t i = ((size_t)blk * 256 + threadIdx.x) * 4;
    float4 v = *(const float4*)(x + i);
    ushort4 o;
    o.x = f2bf(v.x); o.y = f2bf(v.y); o.z = f2bf(v.z); o.w = f2bf(v.w);
    *(ushort4*)(xb + i) = o;
    return;
  }
  const float* in;
  us* out;
  int ldin, ldout, bx, by;
  if (blk < 12288) {
    const int u = blk - 8192;
    in = Wq; out = WqkvT; ldin = 2048; ldout = 2048; bx = u & 63; by = u >> 6;
  } else if (blk < 13312) {
    const int u = blk - 12288;
    in = Wk; out = WqkvT + (size_t)2048 * 2048; ldin = 512; ldout = 2048; bx = u & 15; by = u >> 4;
  } else if (blk < 14336) {
    const int u = blk - 13312;
    in = Wv; out = WqkvT + (size_t)2560 * 2048; ldin = 512; ldout = 2048; bx = u & 15; by = u >> 4;
  } else {
    const int u = blk - 14336;
    in = Wo; out = WoT; ldin = 2048; ldout = 2048; bx = u & 63; by = u >> 6;
  }
  const int c0 = bx * 32, r0 = by * 32;
  const int tx = threadIdx.x & 31, ty = threadIdx.x >> 5;
#pragma unroll
  for (int j = 0; j < 4; ++j)
    tile[ty + j * 8][tx] = in[(size_t)(r0 + ty + j * 8) * ldin + c0 + tx];
  __syncthreads();
#pragma unroll
  for (int j = 0; j < 4; ++j)
    out[(size_t)(c0 + ty + j * 8) * ldout + r0 + tx] = f2bf(tile[tx][ty + j * 8]);
}

// ---------------- bf16 GEMM 256x(64*NF), 2-phase/K-tile, counted vmcnt + XCD swizzle ----------------
// VSPLIT=1 (QKV GEMM): columns >= 2560 (the V slice) are written TRANSPOSED directly into
// VT [b*4+kv][128][2048] (4 contiguous rows per acc reg -> ushort4 store); eliminates tr_v.
template <int NF, int OUTF32, int VSPLIT>
__global__ __launch_bounds__(512, 2) void gemm256(const us* __restrict__ A,
                                                  const us* __restrict__ B,
                                                  void* __restrict__ Cv,
                                                  us* __restrict__ VT,
                                                  int M, int N, int K) {
  __shared__ __attribute__((aligned(16))) us Ah[2][2][256 * 32];
  __shared__ __attribute__((aligned(16))) us Bf[2][64 * NF * 64];
  const int tid = threadIdx.x;
  const int lane = tid & 63;
  const int cl = lane & 15, rg = lane >> 4;
  const int wave = tid >> 6;
  const int wm = wave >> 2, wn = wave & 3;
  const int nwg = gridDim.x * gridDim.y;
  const int bid = blockIdx.x + gridDim.x * blockIdx.y;
  const int swz = (bid & 7) * (nwg >> 3) + (bid >> 3);
  const int bn = swz % gridDim.x, bm = swz / gridDim.x;
  const int NK = K >> 6;
  const int rowA = bm * 256, rowB = bn * (64 * NF);

  f32x4 acc[8][NF] = {};

  auto stage_A = [&](int bf, int h, int kt) {
#pragma unroll
    for (int i = 0; i < 2; ++i) {
      const int L = i * 512 + tid;
      const int r = L >> 2;
      const int c = (L & 3) ^ ((r >> 1) & 3);
      load_lds16(A + (size_t)(rowA + r) * K + kt * 64 + h * 32 + c * 8,
                 &Ah[bf][h][(size_t)(i * 512 + (tid & ~63)) * 8]);
    }
  };
  auto stage_B = [&](int bf, int kt) {
#pragma unroll
    for (int i = 0; i < NF; ++i) {
      const int L = i * 512 + tid;
      const int r = L >> 3;
      const int c = (L & 7) ^ (r & 7);
      load_lds16(B + (size_t)(rowB + r) * K + kt * 64 + c * 8,
                 &Bf[bf][(size_t)(i * 512 + (tid & ~63)) * 8]);
    }
  };

  stage_B(0, 0);
  stage_A(0, 0, 0);
  stage_A(0, 1, 0);
  asm volatile("s_waitcnt vmcnt(2)" ::: "memory");
  __builtin_amdgcn_s_barrier();

  int buf = 0;
#pragma unroll 1
  for (int kt = 0; kt < NK; ++kt) {
    const bool nl = (kt + 1 < NK);
    bf16x8 af[8], bfr[NF];

    // ---- PH0: kk = 0 ----
#pragma unroll
    for (int f = 0; f < 8; ++f) {
      const int r = 128 * wm + 16 * f + cl;
      af[f] = *(const bf16x8*)(&Ah[buf][0][(r * 4 + (rg ^ ((r >> 1) & 3))) * 8]);
    }
#pragma unroll
    for (int nf = 0; nf < NF; ++nf) {
      const int r = 16 * NF * wn + 16 * nf + cl;
      bfr[nf] = *(const bf16x8*)(&Bf[buf][(r * 8 + (rg ^ (r & 7))) * 8]);
    }
    if (nl) stage_B(buf ^ 1, kt + 1);
    __builtin_amdgcn_s_barrier();
    asm volatile("s_waitcnt lgkmcnt(0)" ::: "memory");
    __builtin_amdgcn_s_setprio(1);
#pragma unroll
    for (int f = 0; f < 8; ++f)
#pragma unroll
      for (int nf = 0; nf < NF; ++nf)
        acc[f][nf] = __builtin_amdgcn_mfma_f32_16x16x32_bf16(af[f], bfr[nf], acc[f][nf], 0, 0, 0);
    __builtin_amdgcn_s_setprio(0);
    if (nl) {
      if constexpr (NF == 3) { asm volatile("s_waitcnt vmcnt(3)" ::: "memory"); }
      else                   { asm volatile("s_waitcnt vmcnt(2)" ::: "memory"); }
    } else {
      asm volatile("s_waitcnt vmcnt(0)" ::: "memory");
    }
    __builtin_amdgcn_s_barrier();

    // ---- PH1: kk = 1 ----
#pragma unroll
    for (int f = 0; f < 8; ++f) {
      const int r = 128 * wm + 16 * f + cl;
      af[f] = *(const bf16x8*)(&Ah[buf][1][(r * 4 + (rg ^ ((r >> 1) & 3))) * 8]);
    }
#pragma unroll
    for (int nf = 0; nf < NF; ++nf) {
      const int r = 16 * NF * wn + 16 * nf + cl;
      bfr[nf] = *(const bf16x8*)(&Bf[buf][(r * 8 + ((4 + rg) ^ (r & 7))) * 8]);
    }
    if (nl) { stage_A(buf ^ 1, 0, kt + 1); stage_A(buf ^ 1, 1, kt + 1); }
    __builtin_amdgcn_s_barrier();
    asm volatile("s_waitcnt lgkmcnt(0)" ::: "memory");
    __builtin_amdgcn_s_setprio(1);
#pragma unroll
    for (int f = 0; f < 8; ++f)
#pragma unroll
      for (int nf = 0; nf < NF; ++nf)
        acc[f][nf] = __builtin_amdgcn_mfma_f32_16x16x32_bf16(af[f], bfr[nf], acc[f][nf], 0, 0, 0);
    __builtin_amdgcn_s_setprio(0);
    if (nl) asm volatile("s_waitcnt vmcnt(2)" ::: "memory");
    __builtin_amdgcn_s_barrier();

    buf ^= 1;
  }

#pragma unroll
  for (int f = 0; f < 8; ++f)
#pragma unroll
    for (int nf = 0; nf < NF; ++nf) {
      const int col = bn * 64 * NF + wn * 16 * NF + nf * 16 + cl;
      const int row0 = bm * 256 + wm * 128 + f * 16 + rg * 4;
      if (VSPLIT && col >= 2560) {
        // V slice: write transposed into VT [b*4+kv][128][2048]; rows contiguous -> ushort4
        const int kvv = (col - 2560) >> 7, dcol = (col - 2560) & 127;
        const int bb = row0 >> 11, trow = row0 & 2047;
        ushort4 ov;
        ov.x = f2bf(acc[f][nf][0]);
        ov.y = f2bf(acc[f][nf][1]);
        ov.z = f2bf(acc[f][nf][2]);
        ov.w = f2bf(acc[f][nf][3]);
        *(ushort4*)(&VT[(size_t)((bb * 4 + kvv) * 128 + dcol) * 2048 + trow]) = ov;
      } else {
#pragma unroll
        for (int i = 0; i < 4; ++i) {
          const int row = row0 + i;
          if (OUTF32)
            ((float*)Cv)[(size_t)row * N + col] = acc[f][nf][i];
          else
            ((us*)Cv)[(size_t)row * N + col] = f2bf(acc[f][nf][i]);
        }
      }
    }
}

// ---------------- causal GQA flash attention (round-5 version: measured best, 76 us) ----------------
__global__ __launch_bounds__(256, 2) void attn(const us* __restrict__ QKV,
                                               const us* __restrict__ VT,
                                               us* __restrict__ O) {
  __shared__ __attribute__((aligned(16))) us Ks[2][64 * 128];
  __shared__ __attribute__((aligned(16))) us VTs[2][128 * 64];
  const int T = 2048, LD = 3072, D = 2048;
  const int jp = blockIdx.x, h = blockIdx.y, b = blockIdx.z;
  const int kvh = h >> 2;
  const int tid = threadIdx.x, lane = tid & 63, wave = tid >> 6;
  const int cl = lane & 15, rg = lane >> 4;
  const bool abit = (lane & 16) != 0, bbit = (lane & 32) != 0;
  const bool ab = abit != bbit;
  const us* Kbase = QKV + (size_t)b * T * LD + 2048 + kvh * 128;
  const us* Vbase = VT + (size_t)(b * 4 + kvh) * 128 * T;

  auto stage = [&](int sb, int k0) {
#pragma unroll
    for (int i = 0; i < 4; ++i) {
      const int Ls = i * 256 + tid;
      const int r = Ls >> 4, s = Ls & 15, c = s ^ (r & 7);
      load_lds16(Kbase + (size_t)(k0 + r) * LD + c * 8,
                 &Ks[sb][(i * 256 + (tid & 0xC0)) * 8]);
    }
#pragma unroll
    for (int i = 0; i < 4; ++i) {
      const int Ls = i * 256 + tid;
      const int r = Ls >> 3, s = Ls & 7, c = s ^ (r & 7);
      load_lds16(Vbase + (size_t)r * T + k0 + c * 8,
                 &VTs[sb][(i * 256 + (tid & 0xC0)) * 8]);
    }
  };

  const float scale = 0.08838834764831845f;  // 1/sqrt(128)

#pragma unroll 1
  for (int pass = 0; pass < 2; ++pass) {
    const int jt = pass ? (31 - jp) : jp;
    const int q0 = jt * 64;
    const int nkt = jt + 1;
    const int qrow = q0 + wave * 16 + cl;

    const us* Qp = QKV + (size_t)(b * T + qrow) * LD + h * 128;
    bf16x8 qf[4];
#pragma unroll
    for (int ks = 0; ks < 4; ++ks) qf[ks] = *(const bf16x8*)(Qp + ks * 32 + rg * 8);

    f32x4 o[8] = {};
    float m = -1e30f, l = 0.f;
    int buf = 0;

    stage(0, 0);
    __syncthreads();

#pragma unroll 1
    for (int kt = 0; kt < nkt; ++kt) {
      if (kt + 1 < nkt) stage(buf ^ 1, (kt + 1) * 64);

      f32x4 sa[4] = {};
      __builtin_amdgcn_s_setprio(1);
#pragma unroll
      for (int ks = 0; ks < 4; ++ks) {
#pragma unroll
        for (int n = 0; n < 4; ++n) {
          const int row = n * 16 + cl;
          const int p = (ks * 4 + rg) ^ (row & 7);
          const bf16x8 kf = *(const bf16x8*)(&Ks[buf][row * 128 + p * 8]);
          sa[n] = __builtin_amdgcn_mfma_f32_16x16x32_bf16(kf, qf[ks], sa[n], 0, 0, 0);
        }
      }
      __builtin_amdgcn_s_setprio(0);

      const int k0 = kt * 64;
      float p[4][4];
      float pmax = -1e30f;
      if (kt == jt) {
#pragma unroll
        for (int n = 0; n < 4; ++n)
#pragma unroll
          for (int i = 0; i < 4; ++i) {
            const int kg = k0 + n * 16 + rg * 4 + i;
            p[n][i] = (kg > qrow) ? -1e30f : sa[n][i] * scale;
            pmax = fmaxf(pmax, p[n][i]);
          }
      } else {
#pragma unroll
        for (int n = 0; n < 4; ++n)
#pragma unroll
          for (int i = 0; i < 4; ++i) {
            p[n][i] = sa[n][i] * scale;
            pmax = fmaxf(pmax, p[n][i]);
          }
      }
      pmax = fmaxf(pmax, __shfl_xor(pmax, 16));
      pmax = fmaxf(pmax, __shfl_xor(pmax, 32));

      if (!__all(pmax <= m + 8.f)) {  // T13 defer-max
        const float mnew = fmaxf(m, pmax);
        const float alpha = __expf(m - mnew);
        m = mnew;
        l *= alpha;
#pragma unroll
        for (int n2 = 0; n2 < 8; ++n2) o[n2] *= alpha;
      }

      float rs = 0.f;
#pragma unroll
      for (int n = 0; n < 4; ++n)
#pragma unroll
        for (int i = 0; i < 4; ++i) {
          p[n][i] = __expf(p[n][i] - m);
          rs += p[n][i];
        }
      rs += __shfl_xor(rs, 16);
      rs += __shfl_xor(rs, 32);
      l += rs;

      unsigned int F[2][4];
#pragma unroll
      for (int ks2 = 0; ks2 < 2; ++ks2) {
        const unsigned int pk00 = pack2(p[2 * ks2][0], p[2 * ks2][1]);
        const unsigned int pk01 = pack2(p[2 * ks2][2], p[2 * ks2][3]);
        const unsigned int pk10 = pack2(p[2 * ks2 + 1][0], p[2 * ks2 + 1][1]);
        const unsigned int pk11 = pack2(p[2 * ks2 + 1][2], p[2 * ks2 + 1][3]);
        const unsigned int s0 = bbit ? pk00 : pk10;
        const unsigned int s1 = bbit ? pk01 : pk11;
        const unsigned int r0 = (unsigned int)__shfl_xor((int)s0, 32);
        const unsigned int r1 = (unsigned int)__shfl_xor((int)s1, 32);
        const unsigned int gk0 = bbit ? pk10 : pk00;
        const unsigned int gk1 = bbit ? pk11 : pk01;
        const unsigned int t0 = ab ? gk0 : r0;
        const unsigned int t1 = ab ? gk1 : r1;
        const unsigned int u0 = (unsigned int)__shfl_xor((int)t0, 16);
        const unsigned int u1 = (unsigned int)__shfl_xor((int)t1, 16);
        const unsigned int k20 = ab ? r0 : gk0;
        const unsigned int k21 = ab ? r1 : gk1;
        F[ks2][0] = abit ? u0 : k20;
        F[ks2][1] = abit ? u1 : k21;
        F[ks2][2] = abit ? k20 : u0;
        F[ks2][3] = abit ? k21 : u1;
      }

      __builtin_amdgcn_s_setprio(1);
#pragma unroll
      for (int ks2 = 0; ks2 < 2; ++ks2) {
        uint4 fu = make_uint4(F[ks2][0], F[ks2][1], F[ks2][2], F[ks2][3]);
        const bf16x8 pf = *(const bf16x8*)&fu;
#pragma unroll
        for (int n2 = 0; n2 < 8; ++n2) {
          const int dr = n2 * 16 + cl;
          const int p2 = (ks2 * 4 + rg) ^ (dr & 7);
          const bf16x8 vf = *(const bf16x8*)(&VTs[buf][dr * 64 + p2 * 8]);
          o[n2] = __builtin_amdgcn_mfma_f32_16x16x32_bf16(vf, pf, o[n2], 0, 0, 0);
        }
      }
      __builtin_amdgcn_s_setprio(0);

      __syncthreads();
      buf ^= 1;
    }

    const float rl = __builtin_amdgcn_rcpf(l);
#pragma unroll
    for (int n2 = 0; n2 < 8; ++n2) {
      ushort4 ov;
      ov.x = f2bf(o[n2][0] * rl);
      ov.y = f2bf(o[n2][1] * rl);
      ov.z = f2bf(o[n2][2] * rl);
      ov.w = f2bf(o[n2][3] * rl);
      *(ushort4*)(O + (size_t)(b * T + qrow) * D + h * 128 + n2 * 16 + rg * 4) = ov;
    }
  }
}

extern "C" void kernel_launch(void* const* d_in, const int* in_sizes, int n_in,
                              void* d_out, int out_size, void* d_ws, size_t ws_size,
                              hipStream_t stream) {
  const float* x = (const float*)d_in[0];
  const float* Wq = (const float*)d_in[1];
  const float* Wk = (const float*)d_in[2];
  const float* Wv = (const float*)d_in[3];
  const float* Wo = (const float*)d_in[4];
  float* out = (float*)d_out;

  char* ws = (char*)d_ws;
  us* xb    = (us*)(ws);                 // x bf16, later attn O
  us* WqkvT = (us*)(ws + 16777216);      // [3072][2048]
  us* WoT   = (us*)(ws + 29360128);      // [2048][2048]
  us* QKV   = (us*)(ws + 37748736);      // [4096][3072] (V slice unused)
  us* VTb   = (us*)(ws + 62914560);      // [8][128][2048]

  prep<<<dim3(18432), dim3(256), 0, stream>>>(x, Wq, Wk, Wv, Wo, xb, WqkvT, WoT);
  gemm256<3, 0, 1><<<dim3(16, 16), dim3(512), 0, stream>>>(xb, WqkvT, QKV, VTb, 4096, 3072, 2048);
  attn<<<dim3(16, 16, 2), dim3(256), 0, stream>>>(QKV, VTb, xb);
  gemm256<2, 1, 0><<<dim3(16, 16), dim3(512), 0, stream>>>(xb, WoT, out, nullptr, 4096, 2048, 2048);
}